// Round 2
// baseline (1294.478 us; speedup 1.0000x reference)
//
#include <hip/hip_runtime.h>

// ---------------------------------------------------------------------------
// MambaBlock on MI355X (gfx950).  Pipeline:
//   1. rmsnorm         : x f32 (8192x1024) -> xnorm bf16
//   2. weight packs    : W_in, [W_dt;W_B;W_C;pad] (2176x2048), W_out -> bf16;
//                        A2 = -exp(A_log)*log2(e)
//   3. gemm<SPLIT_IN>  : xnorm @ W_in^T -> x_inner bf16 (cols<2048),
//                        silu(res) bf16 (cols>=2048)   [fused split+silu]
//   4. conv_silu       : depthwise causal K=4 + silu -> xconv bf16
//   5. gemm<SPLIT_DT>  : xconv @ [Wdt;WB;WC]^T; cols<2048 -> softplus(+b_dt)
//                        -> dt f32; cols 2048..2079 -> bc f32 (Mx32)
//   6. scan            : sequential SSM, 16 lanes/channel, *silu(res) -> y bf16
//   7. gemm<PLAIN>     : y @ W_out^T -> d_out f32
// GEMM: m97 structure - 128x128 tile, BK=32, 4 waves, mfma_f32_16x16x32_bf16,
// global_load_lds width=16, unpadded row-major LDS (lane-contiguous).
// Workspace: 173.625 MiB with lifetime aliasing (dt overlays xnorm|win_b|xin).
// Guard: if ws_size < NEEDED, report ws_size via out[0] and bail (absmax
// failure value == actual ws_size -> diagnostic without a core dump).
// ---------------------------------------------------------------------------

typedef __bf16 bf16;
typedef __attribute__((ext_vector_type(8))) __bf16 bf16x8;
typedef __attribute__((ext_vector_type(4))) float f32x4;

#define DIM   1024
#define STATE 16
#define INNER 2048
#define BATCH 4
#define SEQ   2048
#define ROWS  (BATCH * SEQ)      // 8192
#define N1    (2 * INNER)        // 4096 (GEMM1 N)
#define NBC   2176               // 2048 dt + 16 B + 16 C + 96 pad

// async global->LDS, 16 bytes per lane (lane-contiguous LDS dest)
#define GLOAD_LDS16(g, l)                                                  \
  __builtin_amdgcn_global_load_lds(                                        \
      (const __attribute__((address_space(1))) unsigned int*)(g),          \
      (__attribute__((address_space(3))) unsigned int*)(l), 16, 0, 0)

// ---------------------------------------------------------------------------
// 0. workspace-too-small diagnostic
// ---------------------------------------------------------------------------
__global__ void ws_report_kernel(float* out, float wssz, float need) {
  if (threadIdx.x == 0) { out[0] = wssz; out[1] = need; }
}

// ---------------------------------------------------------------------------
// 1. RMSNorm: one block per row (1024 floats), 256 threads x float4
// ---------------------------------------------------------------------------
__global__ __launch_bounds__(256) void rmsnorm_kernel(
    const float* __restrict__ x, const float* __restrict__ w,
    bf16* __restrict__ out) {
  const int row = blockIdx.x;
  const int t = threadIdx.x;
  const float4 v = ((const float4*)(x + (long)row * DIM))[t];
  float ss = v.x * v.x + v.y * v.y + v.z * v.z + v.w * v.w;
#pragma unroll
  for (int off = 32; off > 0; off >>= 1) ss += __shfl_xor(ss, off, 64);
  __shared__ float red[4];
  if ((t & 63) == 0) red[t >> 6] = ss;
  __syncthreads();
  const float tot = red[0] + red[1] + red[2] + red[3];
  const float scale = rsqrtf(tot * (1.0f / DIM) + 1e-6f);
  const float4 wv = ((const float4*)w)[t];
  bf16* o = out + (long)row * DIM + t * 4;
  o[0] = (bf16)(v.x * scale * wv.x);
  o[1] = (bf16)(v.y * scale * wv.y);
  o[2] = (bf16)(v.z * scale * wv.z);
  o[3] = (bf16)(v.w * scale * wv.w);
}

// ---------------------------------------------------------------------------
// 2. weight packs
// ---------------------------------------------------------------------------
__global__ __launch_bounds__(256) void cvt_bf16_kernel(
    const float* __restrict__ src, bf16* __restrict__ dst, int n) {
  const int i = blockIdx.x * 256 + threadIdx.x;
  if (i < n) dst[i] = (bf16)src[i];
}

// dst: NBC x INNER row-major; rows 0..2047 = W_dt, 2048..2063 = W_B,
// 2064..2079 = W_C, rest zero.
__global__ __launch_bounds__(256) void build_wdtbc_kernel(
    const float* __restrict__ Wdt, const float* __restrict__ WB,
    const float* __restrict__ WC, bf16* __restrict__ dst) {
  const long i = (long)blockIdx.x * 256 + threadIdx.x;  // < NBC*INNER
  const long r = i >> 11;  // / INNER
  const long k = i & (INNER - 1);
  float v = 0.0f;
  if (r < 2048) v = Wdt[r * INNER + k];
  else if (r < 2064) v = WB[(r - 2048) * INNER + k];
  else if (r < 2080) v = WC[(r - 2064) * INNER + k];
  dst[i] = (bf16)v;
}

__global__ __launch_bounds__(256) void build_a2_kernel(
    const float* __restrict__ A_log, float* __restrict__ A2) {
  const int i = blockIdx.x * 256 + threadIdx.x;  // < INNER*STATE
  A2[i] = -__expf(A_log[i]) * 1.4426950408889634f;  // A * log2(e)
}

// ---------------------------------------------------------------------------
// 3/5/7. GEMM: C[M,N] = A[M,K] @ B[N,K]^T  (A,B bf16 row-major, f32 acc)
// EPI 0: plain f32 store to Cf (stride N)
// EPI 1: col<2048 -> softplus(acc+bias[col]) -> Cf (stride 2048);
//        2048<=col<2080 -> Cf2 (stride 32); else skip
// EPI 2: col<2048 -> bf16 acc -> Cb (stride 2048);
//        col>=2048 -> bf16 silu(acc) -> Cb2 (stride 2048)
// ---------------------------------------------------------------------------
template <int EPI>
__global__ __launch_bounds__(256) void gemm_bf16_kernel(
    const bf16* __restrict__ A, const bf16* __restrict__ B,
    float* __restrict__ Cf, float* __restrict__ Cf2,
    bf16* __restrict__ Cb, bf16* __restrict__ Cb2,
    const float* __restrict__ bias, int N, int K) {
  __shared__ __align__(16) bf16 As[128 * 32];
  __shared__ __align__(16) bf16 Bs[128 * 32];
  const int tid = threadIdx.x;
  const int lane = tid & 63;
  const int wave = tid >> 6;
  const long row0 = (long)blockIdx.y * 128;
  const long col0 = (long)blockIdx.x * 128;
  const int wr = (wave >> 1) * 64;  // wave row quadrant
  const int wc = (wave & 1) * 64;   // wave col quadrant

  f32x4 acc[4][4];
#pragma unroll
  for (int i = 0; i < 4; i++)
#pragma unroll
    for (int j = 0; j < 4; j++) acc[i][j] = (f32x4){0.f, 0.f, 0.f, 0.f};

  // staging: thread t covers row t>>2 (and +64), elems (t&3)*8 .. +8
  const int srow = tid >> 2;
  const int scol = (tid & 3) * 8;
  const bf16* gA0 = A + (row0 + srow) * (long)K + scol;
  const bf16* gA1 = A + (row0 + srow + 64) * (long)K + scol;
  const bf16* gB0 = B + (col0 + srow) * (long)K + scol;
  const bf16* gB1 = B + (col0 + srow + 64) * (long)K + scol;
  // LDS dest: lane-contiguous (base + lane*16B) == row-major [128][32]
  bf16* lA0 = As + wave * 512 + lane * 8;
  bf16* lA1 = As + 64 * 32 + wave * 512 + lane * 8;
  bf16* lB0 = Bs + wave * 512 + lane * 8;
  bf16* lB1 = Bs + 64 * 32 + wave * 512 + lane * 8;

  const int fm = lane & 15;
  const int fk = (lane >> 4) * 8;

  for (int k0 = 0; k0 < K; k0 += 32) {
    GLOAD_LDS16(gA0 + k0, lA0);
    GLOAD_LDS16(gA1 + k0, lA1);
    GLOAD_LDS16(gB0 + k0, lB0);
    GLOAD_LDS16(gB1 + k0, lB1);
    __syncthreads();
    bf16x8 af[4], bfv[4];
#pragma unroll
    for (int i = 0; i < 4; i++)
      af[i] = *(const bf16x8*)(As + (wr + i * 16 + fm) * 32 + fk);
#pragma unroll
    for (int j = 0; j < 4; j++)
      bfv[j] = *(const bf16x8*)(Bs + (wc + j * 16 + fm) * 32 + fk);
#pragma unroll
    for (int i = 0; i < 4; i++)
#pragma unroll
      for (int j = 0; j < 4; j++)
        acc[i][j] = __builtin_amdgcn_mfma_f32_16x16x32_bf16(
            af[i], bfv[j], acc[i][j], 0, 0, 0);
    __syncthreads();
  }

  // epilogue: C/D layout col=lane&15, row=(lane>>4)*4+reg  [m89/m91 verified]
  const int er = (lane >> 4) * 4;
  const int ec = lane & 15;
#pragma unroll
  for (int i = 0; i < 4; i++) {
#pragma unroll
    for (int j = 0; j < 4; j++) {
      const long col = col0 + wc + j * 16 + ec;
      const long rw = row0 + wr + i * 16 + er;
#pragma unroll
      for (int r = 0; r < 4; r++) {
        const float v = acc[i][j][r];
        const long row = rw + r;
        if (EPI == 0) {
          Cf[row * (long)N + col] = v;
        } else if (EPI == 1) {
          if (col < 2048) {
            float z = v + bias[col];
            z = (z > 20.0f) ? z : log1pf(__expf(z));
            Cf[row * 2048 + col] = z;
          } else if (col < 2080) {
            Cf2[row * 32 + (col - 2048)] = v;
          }
        } else {  // EPI == 2
          if (col < 2048) {
            Cb[row * 2048 + col] = (bf16)v;
          } else {
            const float s = v / (1.0f + __expf(-v));
            Cb2[row * 2048 + (col - 2048)] = (bf16)s;
          }
        }
      }
    }
  }
}

// ---------------------------------------------------------------------------
// 4. depthwise causal conv (K=4) + silu.  xin: ROWS x 2048 bf16
// ---------------------------------------------------------------------------
__global__ __launch_bounds__(256) void conv_silu_kernel(
    const bf16* __restrict__ xin, const float* __restrict__ conv_w,
    const float* __restrict__ conv_b, bf16* __restrict__ xc16) {
  const int c = blockIdx.x * 256 + threadIdx.x;  // channel 0..2047
  const int r = blockIdx.y;                      // global row 0..8191
  const int l = r & (SEQ - 1);                   // position within sequence
  const float4 w = *(const float4*)(conv_w + c * 4);
  float acc = conv_b[c];
#pragma unroll
  for (int j = 0; j < 4; j++) {
    const int lp = l - 3 + j;
    const float xv = (lp >= 0) ? (float)xin[(long)(r - 3 + j) * INNER + c] : 0.0f;
    acc += xv * ((const float*)&w)[j];
  }
  const float s = acc / (1.0f + __expf(-acc));  // silu
  xc16[(long)r * INNER + c] = (bf16)s;
}

// ---------------------------------------------------------------------------
// 6. sequential SSM scan. 16 lanes per channel (one per state), 16 ch/block.
// ---------------------------------------------------------------------------
__global__ __launch_bounds__(256) void scan_kernel(
    const float* __restrict__ dtm,      // ROWS x 2048 (softplus'd)
    const float* __restrict__ bc,       // ROWS x 32 (B | C)
    const bf16* __restrict__ xc,        // ROWS x 2048
    const bf16* __restrict__ res_silu,  // ROWS x 2048 (silu pre-applied)
    const float* __restrict__ A2,       // INNER x STATE (A*log2e)
    const float* __restrict__ Dv,       // INNER
    bf16* __restrict__ y) {             // ROWS x 2048
  const int s = threadIdx.x & 15;
  const int g = threadIdx.x >> 4;               // 0..15
  const int i = blockIdx.x * 16 + g;            // channel
  const long rowbase = (long)blockIdx.y * SEQ;  // batch offset
  const float a2 = A2[i * STATE + s];
  const float d = Dv[i];
  float h = 0.0f;

  // software pipeline: prefetch next row's operands one iteration ahead
  float dt_n = dtm[rowbase * INNER + i];
  float Bt_n = bc[rowbase * 32 + s];
  float Ct_n = bc[rowbase * 32 + 16 + s];
  float xc_n = (float)xc[rowbase * INNER + i];
  float rs_n = (float)res_silu[rowbase * INNER + i];

  for (int l = 0; l < SEQ; l++) {
    const float dt = dt_n, Bt = Bt_n, Ct = Ct_n, xcv = xc_n, rs = rs_n;
    if (l + 1 < SEQ) {
      const long r2 = rowbase + l + 1;
      dt_n = dtm[r2 * INNER + i];
      Bt_n = bc[r2 * 32 + s];
      Ct_n = bc[r2 * 32 + 16 + s];
      xc_n = (float)xc[r2 * INNER + i];
      rs_n = (float)res_silu[r2 * INNER + i];
    }
    const float dA = exp2f(a2 * dt);
    h = dA * h + (dt * Bt) * xcv;
    float v = h * Ct;
    v += __shfl_xor(v, 1, 16);
    v += __shfl_xor(v, 2, 16);
    v += __shfl_xor(v, 4, 16);
    v += __shfl_xor(v, 8, 16);
    if (s == 0) {
      const float yv = (v + d * xcv) * rs;
      y[(rowbase + l) * INNER + i] = (bf16)yv;
    }
  }
}

// ---------------------------------------------------------------------------
// launch
// ---------------------------------------------------------------------------
extern "C" void kernel_launch(void* const* d_in, const int* in_sizes, int n_in,
                              void* d_out, int out_size, void* d_ws,
                              size_t ws_size, hipStream_t stream) {
  (void)in_sizes; (void)n_in; (void)out_size;
  const float* x      = (const float*)d_in[0];
  const float* w_norm = (const float*)d_in[1];
  const float* W_in   = (const float*)d_in[2];
  const float* conv_w = (const float*)d_in[3];
  const float* conv_b = (const float*)d_in[4];
  const float* W_dt   = (const float*)d_in[5];
  const float* b_dt   = (const float*)d_in[6];
  const float* W_B    = (const float*)d_in[7];
  const float* W_C    = (const float*)d_in[8];
  const float* A_log  = (const float*)d_in[9];
  const float* Dv     = (const float*)d_in[10];
  const float* W_out  = (const float*)d_in[11];
  float* out = (float*)d_out;

  // ---- workspace layout (lifetime-aliased, 173.625 MiB total) -------------
  const size_t MB = 1024ull * 1024ull;
  char* base = (char*)d_ws;
  // T1..T2 region, later overlaid by dt (f32, T4..T5):
  bf16*  xnorm  = (bf16*)(base + 0);          // 16 MiB [rmsnorm -> gemm1]
  bf16*  win_b  = (bf16*)(base + 16 * MB);    //  8 MiB [pack -> gemm1]
  bf16*  xin_b  = (bf16*)(base + 24 * MB);    // 32 MiB [gemm1 -> conv]
  float* dtm    = (float*)(base + 0);         // 64 MiB [gemm2 -> scan] ALIAS
  float* bcm    = (float*)(base + 64 * MB);   //  1 MiB [gemm2 -> scan]
  bf16*  res_b  = (bf16*)(base + 65 * MB);    // 32 MiB [gemm1 -> scan]
  bf16*  xc_b   = (bf16*)(base + 97 * MB);    // 32 MiB [conv -> gemm2, scan]
  bf16*  wdtbcb = (bf16*)(base + 129 * MB);   // 8.5 MiB [pack -> gemm2]
  char*  p2     = base + 129 * MB + (size_t)NBC * INNER * 2;
  bf16*  wout_b = (bf16*)p2;                  //  4 MiB [pack -> gemm3]
  float* A2     = (float*)(p2 + (size_t)DIM * INNER * 2);  // 128 KiB
  bf16*  yb     = (bf16*)(p2 + (size_t)DIM * INNER * 2 +
                          (size_t)INNER * STATE * 4);      // 32 MiB [scan->g3]
  const size_t NEEDED = (size_t)((char*)yb - base) + (size_t)ROWS * INNER * 2;

  if (ws_size < NEEDED) {  // diagnostic: fail with absmax == ws_size
    ws_report_kernel<<<1, 64, 0, stream>>>(out, (float)ws_size, (float)NEEDED);
    return;
  }

  // 1. rmsnorm -> xnorm bf16
  rmsnorm_kernel<<<ROWS, 256, 0, stream>>>(x, w_norm, xnorm);

  // 2. weight packs
  cvt_bf16_kernel<<<(N1 * DIM) / 256, 256, 0, stream>>>(W_in, win_b, N1 * DIM);
  build_wdtbc_kernel<<<(NBC * INNER) / 256, 256, 0, stream>>>(W_dt, W_B, W_C,
                                                              wdtbcb);
  cvt_bf16_kernel<<<(DIM * INNER) / 256, 256, 0, stream>>>(W_out, wout_b,
                                                           DIM * INNER);
  build_a2_kernel<<<(INNER * STATE) / 256, 256, 0, stream>>>(A_log, A2);

  // 3. GEMM1: xnorm(8192x1024) @ W_in^T(4096x1024) -> xin_b | silu->res_b
  gemm_bf16_kernel<2><<<dim3(N1 / 128, ROWS / 128), 256, 0, stream>>>(
      xnorm, win_b, nullptr, nullptr, xin_b, res_b, nullptr, N1, DIM);

  // 4. conv + silu -> xc_b
  conv_silu_kernel<<<dim3(INNER / 256, ROWS), 256, 0, stream>>>(
      xin_b, conv_w, conv_b, xc_b);

  // 5. GEMM2: xc_b(8192x2048) @ [Wdt;WB;WC]^T(2176x2048) -> dtm | bcm
  gemm_bf16_kernel<1><<<dim3(NBC / 128, ROWS / 128), 256, 0, stream>>>(
      xc_b, wdtbcb, dtm, bcm, nullptr, nullptr, b_dt, NBC, INNER);

  // 6. scan -> yb
  scan_kernel<<<dim3(INNER / 16, BATCH), 256, 0, stream>>>(dtm, bcm, xc_b,
                                                           res_b, A2, Dv, yb);

  // 7. GEMM3: yb(8192x2048) @ W_out^T(1024x2048) -> out f32
  gemm_bf16_kernel<0><<<dim3(DIM / 128, ROWS / 128), 256, 0, stream>>>(
      yb, wout_b, out, nullptr, nullptr, nullptr, nullptr, DIM, INNER);
}

// Round 3
// 1010.450 us; speedup vs baseline: 1.2811x; 1.2811x over previous
//
#include <hip/hip_runtime.h>

// ---------------------------------------------------------------------------
// MambaBlock on MI355X (gfx950).  Pipeline:
//   1. rmsnorm         : x f32 (8192x1024) -> xnorm bf16
//   2. weight packs    : W_in, [W_dt;W_B;W_C;pad] (2176x2048), W_out -> bf16;
//                        A2 = -exp(A_log)*log2(e)
//   3. gemm<SPLIT_IN>  : xnorm @ W_in^T -> x_inner bf16 (cols<2048),
//                        silu(res) bf16 (cols>=2048)   [fused split+silu]
//   4. conv_silu       : depthwise causal K=4 + silu -> xconv bf16
//   5. gemm<SPLIT_DT>  : xconv @ [Wdt;WB;WC]^T; cols<2048 -> softplus(+b_dt)
//                        -> dt f32; cols 2048..2079 -> bc f32 (Mx32)
//   6. scan            : sequential SSM, 16 lanes/channel, 16-deep register
//                        prefetch (R3: was 1-deep -> 927 cyc/iter latency-bound)
//   7. gemm<PLAIN>     : y @ W_out^T -> d_out f32
// GEMM: m97 structure - 128x128 tile, BK=32, 4 waves, mfma_f32_16x16x32_bf16,
// global_load_lds width=16, unpadded row-major LDS (lane-contiguous).
// Workspace: 173.625 MiB with lifetime aliasing (dt overlays xnorm|win_b|xin).
// ---------------------------------------------------------------------------

typedef __bf16 bf16;
typedef __attribute__((ext_vector_type(8))) __bf16 bf16x8;
typedef __attribute__((ext_vector_type(4))) float f32x4;

#define DIM   1024
#define STATE 16
#define INNER 2048
#define BATCH 4
#define SEQ   2048
#define ROWS  (BATCH * SEQ)      // 8192
#define N1    (2 * INNER)        // 4096 (GEMM1 N)
#define NBC   2176               // 2048 dt + 16 B + 16 C + 96 pad
#define PF    16                 // scan prefetch depth (rows)

// async global->LDS, 16 bytes per lane (lane-contiguous LDS dest)
#define GLOAD_LDS16(g, l)                                                  \
  __builtin_amdgcn_global_load_lds(                                        \
      (const __attribute__((address_space(1))) unsigned int*)(g),          \
      (__attribute__((address_space(3))) unsigned int*)(l), 16, 0, 0)

// ---------------------------------------------------------------------------
// 0. workspace-too-small diagnostic
// ---------------------------------------------------------------------------
__global__ void ws_report_kernel(float* out, float wssz, float need) {
  if (threadIdx.x == 0) { out[0] = wssz; out[1] = need; }
}

// ---------------------------------------------------------------------------
// 1. RMSNorm: one block per row (1024 floats), 256 threads x float4
// ---------------------------------------------------------------------------
__global__ __launch_bounds__(256) void rmsnorm_kernel(
    const float* __restrict__ x, const float* __restrict__ w,
    bf16* __restrict__ out) {
  const int row = blockIdx.x;
  const int t = threadIdx.x;
  const float4 v = ((const float4*)(x + (long)row * DIM))[t];
  float ss = v.x * v.x + v.y * v.y + v.z * v.z + v.w * v.w;
#pragma unroll
  for (int off = 32; off > 0; off >>= 1) ss += __shfl_xor(ss, off, 64);
  __shared__ float red[4];
  if ((t & 63) == 0) red[t >> 6] = ss;
  __syncthreads();
  const float tot = red[0] + red[1] + red[2] + red[3];
  const float scale = rsqrtf(tot * (1.0f / DIM) + 1e-6f);
  const float4 wv = ((const float4*)w)[t];
  bf16* o = out + (long)row * DIM + t * 4;
  o[0] = (bf16)(v.x * scale * wv.x);
  o[1] = (bf16)(v.y * scale * wv.y);
  o[2] = (bf16)(v.z * scale * wv.z);
  o[3] = (bf16)(v.w * scale * wv.w);
}

// ---------------------------------------------------------------------------
// 2. weight packs
// ---------------------------------------------------------------------------
__global__ __launch_bounds__(256) void cvt_bf16_kernel(
    const float* __restrict__ src, bf16* __restrict__ dst, int n) {
  const int i = blockIdx.x * 256 + threadIdx.x;
  if (i < n) dst[i] = (bf16)src[i];
}

// dst: NBC x INNER row-major; rows 0..2047 = W_dt, 2048..2063 = W_B,
// 2064..2079 = W_C, rest zero.
__global__ __launch_bounds__(256) void build_wdtbc_kernel(
    const float* __restrict__ Wdt, const float* __restrict__ WB,
    const float* __restrict__ WC, bf16* __restrict__ dst) {
  const long i = (long)blockIdx.x * 256 + threadIdx.x;  // < NBC*INNER
  const long r = i >> 11;  // / INNER
  const long k = i & (INNER - 1);
  float v = 0.0f;
  if (r < 2048) v = Wdt[r * INNER + k];
  else if (r < 2064) v = WB[(r - 2048) * INNER + k];
  else if (r < 2080) v = WC[(r - 2064) * INNER + k];
  dst[i] = (bf16)v;
}

__global__ __launch_bounds__(256) void build_a2_kernel(
    const float* __restrict__ A_log, float* __restrict__ A2) {
  const int i = blockIdx.x * 256 + threadIdx.x;  // < INNER*STATE
  A2[i] = -__expf(A_log[i]) * 1.4426950408889634f;  // A * log2(e)
}

// ---------------------------------------------------------------------------
// 3/5/7. GEMM: C[M,N] = A[M,K] @ B[N,K]^T  (A,B bf16 row-major, f32 acc)
// EPI 0: plain f32 store to Cf (stride N)
// EPI 1: col<2048 -> softplus(acc+bias[col]) -> Cf (stride 2048);
//        2048<=col<2080 -> Cf2 (stride 32); else skip
// EPI 2: col<2048 -> bf16 acc -> Cb (stride 2048);
//        col>=2048 -> bf16 silu(acc) -> Cb2 (stride 2048)
// ---------------------------------------------------------------------------
template <int EPI>
__global__ __launch_bounds__(256) void gemm_bf16_kernel(
    const bf16* __restrict__ A, const bf16* __restrict__ B,
    float* __restrict__ Cf, float* __restrict__ Cf2,
    bf16* __restrict__ Cb, bf16* __restrict__ Cb2,
    const float* __restrict__ bias, int N, int K) {
  __shared__ __align__(16) bf16 As[128 * 32];
  __shared__ __align__(16) bf16 Bs[128 * 32];
  const int tid = threadIdx.x;
  const int lane = tid & 63;
  const int wave = tid >> 6;
  const long row0 = (long)blockIdx.y * 128;
  const long col0 = (long)blockIdx.x * 128;
  const int wr = (wave >> 1) * 64;  // wave row quadrant
  const int wc = (wave & 1) * 64;   // wave col quadrant

  f32x4 acc[4][4];
#pragma unroll
  for (int i = 0; i < 4; i++)
#pragma unroll
    for (int j = 0; j < 4; j++) acc[i][j] = (f32x4){0.f, 0.f, 0.f, 0.f};

  // staging: thread t covers row t>>2 (and +64), elems (t&3)*8 .. +8
  const int srow = tid >> 2;
  const int scol = (tid & 3) * 8;
  const bf16* gA0 = A + (row0 + srow) * (long)K + scol;
  const bf16* gA1 = A + (row0 + srow + 64) * (long)K + scol;
  const bf16* gB0 = B + (col0 + srow) * (long)K + scol;
  const bf16* gB1 = B + (col0 + srow + 64) * (long)K + scol;
  // LDS dest: lane-contiguous (base + lane*16B) == row-major [128][32]
  bf16* lA0 = As + wave * 512 + lane * 8;
  bf16* lA1 = As + 64 * 32 + wave * 512 + lane * 8;
  bf16* lB0 = Bs + wave * 512 + lane * 8;
  bf16* lB1 = Bs + 64 * 32 + wave * 512 + lane * 8;

  const int fm = lane & 15;
  const int fk = (lane >> 4) * 8;

  for (int k0 = 0; k0 < K; k0 += 32) {
    GLOAD_LDS16(gA0 + k0, lA0);
    GLOAD_LDS16(gA1 + k0, lA1);
    GLOAD_LDS16(gB0 + k0, lB0);
    GLOAD_LDS16(gB1 + k0, lB1);
    __syncthreads();
    bf16x8 af[4], bfv[4];
#pragma unroll
    for (int i = 0; i < 4; i++)
      af[i] = *(const bf16x8*)(As + (wr + i * 16 + fm) * 32 + fk);
#pragma unroll
    for (int j = 0; j < 4; j++)
      bfv[j] = *(const bf16x8*)(Bs + (wc + j * 16 + fm) * 32 + fk);
#pragma unroll
    for (int i = 0; i < 4; i++)
#pragma unroll
      for (int j = 0; j < 4; j++)
        acc[i][j] = __builtin_amdgcn_mfma_f32_16x16x32_bf16(
            af[i], bfv[j], acc[i][j], 0, 0, 0);
    __syncthreads();
  }

  // epilogue: C/D layout col=lane&15, row=(lane>>4)*4+reg  [m89/m91 verified]
  const int er = (lane >> 4) * 4;
  const int ec = lane & 15;
#pragma unroll
  for (int i = 0; i < 4; i++) {
#pragma unroll
    for (int j = 0; j < 4; j++) {
      const long col = col0 + wc + j * 16 + ec;
      const long rw = row0 + wr + i * 16 + er;
#pragma unroll
      for (int r = 0; r < 4; r++) {
        const float v = acc[i][j][r];
        const long row = rw + r;
        if (EPI == 0) {
          Cf[row * (long)N + col] = v;
        } else if (EPI == 1) {
          if (col < 2048) {
            float z = v + bias[col];
            z = (z > 20.0f) ? z : log1pf(__expf(z));
            Cf[row * 2048 + col] = z;
          } else if (col < 2080) {
            Cf2[row * 32 + (col - 2048)] = v;
          }
        } else {  // EPI == 2
          if (col < 2048) {
            Cb[row * 2048 + col] = (bf16)v;
          } else {
            const float s = v / (1.0f + __expf(-v));
            Cb2[row * 2048 + (col - 2048)] = (bf16)s;
          }
        }
      }
    }
  }
}

// ---------------------------------------------------------------------------
// 4. depthwise causal conv (K=4) + silu.  xin: ROWS x 2048 bf16
// ---------------------------------------------------------------------------
__global__ __launch_bounds__(256) void conv_silu_kernel(
    const bf16* __restrict__ xin, const float* __restrict__ conv_w,
    const float* __restrict__ conv_b, bf16* __restrict__ xc16) {
  const int c = blockIdx.x * 256 + threadIdx.x;  // channel 0..2047
  const int r = blockIdx.y;                      // global row 0..8191
  const int l = r & (SEQ - 1);                   // position within sequence
  const float4 w = *(const float4*)(conv_w + c * 4);
  float acc = conv_b[c];
#pragma unroll
  for (int j = 0; j < 4; j++) {
    const int lp = l - 3 + j;
    const float xv = (lp >= 0) ? (float)xin[(long)(r - 3 + j) * INNER + c] : 0.0f;
    acc += xv * ((const float*)&w)[j];
  }
  const float s = acc / (1.0f + __expf(-acc));  // silu
  xc16[(long)r * INNER + c] = (bf16)s;
}

// ---------------------------------------------------------------------------
// 6. sequential SSM scan. 16 lanes/channel (one per state), 16 ch/block.
// R3: 16-row-deep register prefetch queue. The recurrence only carries h;
// all operand loads are independent -> keep ~60 loads in flight (vmcnt cap
// 63) so per-iter cost ~ latency/12 instead of full latency (927 cyc, R2).
// ---------------------------------------------------------------------------
__global__ __launch_bounds__(256) void scan_kernel(
    const float* __restrict__ dtm,      // ROWS x 2048 (softplus'd)
    const float* __restrict__ bc,       // ROWS x 32 (B | C)
    const bf16* __restrict__ xc,        // ROWS x 2048
    const bf16* __restrict__ res_silu,  // ROWS x 2048 (silu pre-applied)
    const float* __restrict__ A2,       // INNER x STATE (A*log2e)
    const float* __restrict__ Dv,       // INNER
    bf16* __restrict__ y) {             // ROWS x 2048
  const int s = threadIdx.x & 15;
  const int g = threadIdx.x >> 4;               // 0..15
  const int i = blockIdx.x * 16 + g;            // channel
  const long rowbase = (long)blockIdx.y * SEQ;  // batch offset
  const float a2 = A2[i * STATE + s];
  const float d = Dv[i];
  float h = 0.0f;

  float dt_q[PF], Bt_q[PF], Ct_q[PF], xc_q[PF], rs_q[PF];
#pragma unroll
  for (int p = 0; p < PF; p++) {
    const long r2 = rowbase + p;
    dt_q[p] = dtm[r2 * INNER + i];
    Bt_q[p] = bc[r2 * 32 + s];
    Ct_q[p] = bc[r2 * 32 + 16 + s];
    xc_q[p] = (float)xc[r2 * INNER + i];
    rs_q[p] = (float)res_silu[r2 * INNER + i];
  }

  // main loop: rows 0 .. SEQ-PF-1, prefetching row l+PF into slot p
  for (int l0 = 0; l0 < SEQ - PF; l0 += PF) {
#pragma unroll
    for (int p = 0; p < PF; p++) {
      const int l = l0 + p;
      const float dt = dt_q[p], Bt = Bt_q[p], Ct = Ct_q[p],
                  xcv = xc_q[p], rs = rs_q[p];
      const long r2 = rowbase + l + PF;
      dt_q[p] = dtm[r2 * INNER + i];
      Bt_q[p] = bc[r2 * 32 + s];
      Ct_q[p] = bc[r2 * 32 + 16 + s];
      xc_q[p] = (float)xc[r2 * INNER + i];
      rs_q[p] = (float)res_silu[r2 * INNER + i];
      const float dA = exp2f(a2 * dt);
      h = dA * h + (dt * Bt) * xcv;
      float v = h * Ct;
      v += __shfl_xor(v, 1, 16);
      v += __shfl_xor(v, 2, 16);
      v += __shfl_xor(v, 4, 16);
      v += __shfl_xor(v, 8, 16);
      if (s == 0) {
        const float yv = (v + d * xcv) * rs;
        y[(rowbase + l) * INNER + i] = (bf16)yv;
      }
    }
  }

  // tail: last PF rows, no prefetch
#pragma unroll
  for (int p = 0; p < PF; p++) {
    const int l = SEQ - PF + p;
    const float dt = dt_q[p], Bt = Bt_q[p], Ct = Ct_q[p],
                xcv = xc_q[p], rs = rs_q[p];
    const float dA = exp2f(a2 * dt);
    h = dA * h + (dt * Bt) * xcv;
    float v = h * Ct;
    v += __shfl_xor(v, 1, 16);
    v += __shfl_xor(v, 2, 16);
    v += __shfl_xor(v, 4, 16);
    v += __shfl_xor(v, 8, 16);
    if (s == 0) {
      const float yv = (v + d * xcv) * rs;
      y[(rowbase + l) * INNER + i] = (bf16)yv;
    }
  }
}

// ---------------------------------------------------------------------------
// launch
// ---------------------------------------------------------------------------
extern "C" void kernel_launch(void* const* d_in, const int* in_sizes, int n_in,
                              void* d_out, int out_size, void* d_ws,
                              size_t ws_size, hipStream_t stream) {
  (void)in_sizes; (void)n_in; (void)out_size;
  const float* x      = (const float*)d_in[0];
  const float* w_norm = (const float*)d_in[1];
  const float* W_in   = (const float*)d_in[2];
  const float* conv_w = (const float*)d_in[3];
  const float* conv_b = (const float*)d_in[4];
  const float* W_dt   = (const float*)d_in[5];
  const float* b_dt   = (const float*)d_in[6];
  const float* W_B    = (const float*)d_in[7];
  const float* W_C    = (const float*)d_in[8];
  const float* A_log  = (const float*)d_in[9];
  const float* Dv     = (const float*)d_in[10];
  const float* W_out  = (const float*)d_in[11];
  float* out = (float*)d_out;

  // ---- workspace layout (lifetime-aliased, 173.625 MiB total) -------------
  const size_t MB = 1024ull * 1024ull;
  char* base = (char*)d_ws;
  bf16*  xnorm  = (bf16*)(base + 0);          // 16 MiB [rmsnorm -> gemm1]
  bf16*  win_b  = (bf16*)(base + 16 * MB);    //  8 MiB [pack -> gemm1]
  bf16*  xin_b  = (bf16*)(base + 24 * MB);    // 32 MiB [gemm1 -> conv]
  float* dtm    = (float*)(base + 0);         // 64 MiB [gemm2 -> scan] ALIAS
  float* bcm    = (float*)(base + 64 * MB);   //  1 MiB [gemm2 -> scan]
  bf16*  res_b  = (bf16*)(base + 65 * MB);    // 32 MiB [gemm1 -> scan]
  bf16*  xc_b   = (bf16*)(base + 97 * MB);    // 32 MiB [conv -> gemm2, scan]
  bf16*  wdtbcb = (bf16*)(base + 129 * MB);   // 8.5 MiB [pack -> gemm2]
  char*  p2     = base + 129 * MB + (size_t)NBC * INNER * 2;
  bf16*  wout_b = (bf16*)p2;                  //  4 MiB [pack -> gemm3]
  float* A2     = (float*)(p2 + (size_t)DIM * INNER * 2);  // 128 KiB
  bf16*  yb     = (bf16*)(p2 + (size_t)DIM * INNER * 2 +
                          (size_t)INNER * STATE * 4);      // 32 MiB [scan->g3]
  const size_t NEEDED = (size_t)((char*)yb - base) + (size_t)ROWS * INNER * 2;

  if (ws_size < NEEDED) {  // diagnostic: fail with absmax == ws_size
    ws_report_kernel<<<1, 64, 0, stream>>>(out, (float)ws_size, (float)NEEDED);
    return;
  }

  // 1. rmsnorm -> xnorm bf16
  rmsnorm_kernel<<<ROWS, 256, 0, stream>>>(x, w_norm, xnorm);

  // 2. weight packs
  cvt_bf16_kernel<<<(N1 * DIM) / 256, 256, 0, stream>>>(W_in, win_b, N1 * DIM);
  build_wdtbc_kernel<<<(NBC * INNER) / 256, 256, 0, stream>>>(W_dt, W_B, W_C,
                                                              wdtbcb);
  cvt_bf16_kernel<<<(DIM * INNER) / 256, 256, 0, stream>>>(W_out, wout_b,
                                                           DIM * INNER);
  build_a2_kernel<<<(INNER * STATE) / 256, 256, 0, stream>>>(A_log, A2);

  // 3. GEMM1: xnorm(8192x1024) @ W_in^T(4096x1024) -> xin_b | silu->res_b
  gemm_bf16_kernel<2><<<dim3(N1 / 128, ROWS / 128), 256, 0, stream>>>(
      xnorm, win_b, nullptr, nullptr, xin_b, res_b, nullptr, N1, DIM);

  // 4. conv + silu -> xc_b
  conv_silu_kernel<<<dim3(INNER / 256, ROWS), 256, 0, stream>>>(
      xin_b, conv_w, conv_b, xc_b);

  // 5. GEMM2: xc_b(8192x2048) @ [Wdt;WB;WC]^T(2176x2048) -> dtm | bcm
  gemm_bf16_kernel<1><<<dim3(NBC / 128, ROWS / 128), 256, 0, stream>>>(
      xc_b, wdtbcb, dtm, bcm, nullptr, nullptr, b_dt, NBC, INNER);

  // 6. scan -> yb
  scan_kernel<<<dim3(INNER / 16, BATCH), 256, 0, stream>>>(dtm, bcm, xc_b,
                                                           res_b, A2, Dv, yb);

  // 7. GEMM3: yb(8192x2048) @ W_out^T(1024x2048) -> out f32
  gemm_bf16_kernel<0><<<dim3(DIM / 128, ROWS / 128), 256, 0, stream>>>(
      yb, wout_b, out, nullptr, nullptr, nullptr, nullptr, DIM, INNER);
}

// Round 4
// 706.069 us; speedup vs baseline: 1.8334x; 1.4311x over previous
//
#include <hip/hip_runtime.h>

// ---------------------------------------------------------------------------
// MambaBlock on MI355X (gfx950).  Pipeline:
//   1. rmsnorm         : x f32 (8192x1024) -> xnorm bf16
//   2. weight packs    : W_in, [W_dt;W_B;W_C;pad] (2176x2048), W_out -> bf16;
//                        A2 = -exp(A_log)*log2(e)
//   3. gemm<SPLIT_IN>  : xnorm @ W_in^T -> x_inner bf16 | silu(res) bf16
//   4. conv_silu       : depthwise causal K=4 + silu -> xconv bf16
//   5. gemm<SPLIT_DT>  : xconv @ [Wdt;WB;WC]^T -> dt f32 (softplus) | bc f32
//   6. scan (R4)       : chunked two-pass associative scan, channel-per-lane:
//                        pass1 (zero-init chunk scans + dt-sums) -> combine
//                        (chunk-boundary states, 16 steps) -> pass3 (re-scan
//                        with true h_start, y + gating).  R3's 16-lane/channel
//                        layout was latency-bound (603 cyc/row: shfl chain +
//                        1 MAC/lane density); this is 16 MACs/lane, no shfl,
//                        all loads coalesced, B/C wave-uniform (s_load).
//   7. gemm<PLAIN>     : y @ W_out^T -> d_out f32
// GEMM: m97 structure - 128x128 tile, BK=32, 4 waves, mfma_f32_16x16x32_bf16.
// Workspace: 173.625 MiB; chunk state (8.5 MB) aliases dead wdtbcb region.
// ---------------------------------------------------------------------------

typedef __bf16 bf16;
typedef __attribute__((ext_vector_type(8))) __bf16 bf16x8;
typedef __attribute__((ext_vector_type(4))) float f32x4;

#define DIM   1024
#define STATE 16
#define INNER 2048
#define BATCH 4
#define SEQ   2048
#define ROWS  (BATCH * SEQ)      // 8192
#define N1    (2 * INNER)        // 4096 (GEMM1 N)
#define NBC   2176               // 2048 dt + 16 B + 16 C + 96 pad
#define CHUNK 128                // scan chunk length
#define NC    (SEQ / CHUNK)      // 16 chunks per sequence
#define PF2   4                  // scan prefetch depth (rows)

// async global->LDS, 16 bytes per lane (lane-contiguous LDS dest)
#define GLOAD_LDS16(g, l)                                                  \
  __builtin_amdgcn_global_load_lds(                                        \
      (const __attribute__((address_space(1))) unsigned int*)(g),          \
      (__attribute__((address_space(3))) unsigned int*)(l), 16, 0, 0)

// ---------------------------------------------------------------------------
// 0. workspace-too-small diagnostic
// ---------------------------------------------------------------------------
__global__ void ws_report_kernel(float* out, float wssz, float need) {
  if (threadIdx.x == 0) { out[0] = wssz; out[1] = need; }
}

// ---------------------------------------------------------------------------
// 1. RMSNorm: one block per row (1024 floats), 256 threads x float4
// ---------------------------------------------------------------------------
__global__ __launch_bounds__(256) void rmsnorm_kernel(
    const float* __restrict__ x, const float* __restrict__ w,
    bf16* __restrict__ out) {
  const int row = blockIdx.x;
  const int t = threadIdx.x;
  const float4 v = ((const float4*)(x + (long)row * DIM))[t];
  float ss = v.x * v.x + v.y * v.y + v.z * v.z + v.w * v.w;
#pragma unroll
  for (int off = 32; off > 0; off >>= 1) ss += __shfl_xor(ss, off, 64);
  __shared__ float red[4];
  if ((t & 63) == 0) red[t >> 6] = ss;
  __syncthreads();
  const float tot = red[0] + red[1] + red[2] + red[3];
  const float scale = rsqrtf(tot * (1.0f / DIM) + 1e-6f);
  const float4 wv = ((const float4*)w)[t];
  bf16* o = out + (long)row * DIM + t * 4;
  o[0] = (bf16)(v.x * scale * wv.x);
  o[1] = (bf16)(v.y * scale * wv.y);
  o[2] = (bf16)(v.z * scale * wv.z);
  o[3] = (bf16)(v.w * scale * wv.w);
}

// ---------------------------------------------------------------------------
// 2. weight packs
// ---------------------------------------------------------------------------
__global__ __launch_bounds__(256) void cvt_bf16_kernel(
    const float* __restrict__ src, bf16* __restrict__ dst, int n) {
  const int i = blockIdx.x * 256 + threadIdx.x;
  if (i < n) dst[i] = (bf16)src[i];
}

__global__ __launch_bounds__(256) void build_wdtbc_kernel(
    const float* __restrict__ Wdt, const float* __restrict__ WB,
    const float* __restrict__ WC, bf16* __restrict__ dst) {
  const long i = (long)blockIdx.x * 256 + threadIdx.x;  // < NBC*INNER
  const long r = i >> 11;  // / INNER
  const long k = i & (INNER - 1);
  float v = 0.0f;
  if (r < 2048) v = Wdt[r * INNER + k];
  else if (r < 2064) v = WB[(r - 2048) * INNER + k];
  else if (r < 2080) v = WC[(r - 2064) * INNER + k];
  dst[i] = (bf16)v;
}

__global__ __launch_bounds__(256) void build_a2_kernel(
    const float* __restrict__ A_log, float* __restrict__ A2) {
  const int i = blockIdx.x * 256 + threadIdx.x;  // < INNER*STATE
  A2[i] = -__expf(A_log[i]) * 1.4426950408889634f;  // A * log2(e)
}

// ---------------------------------------------------------------------------
// 3/5/7. GEMM: C[M,N] = A[M,K] @ B[N,K]^T  (A,B bf16 row-major, f32 acc)
// ---------------------------------------------------------------------------
template <int EPI>
__global__ __launch_bounds__(256) void gemm_bf16_kernel(
    const bf16* __restrict__ A, const bf16* __restrict__ B,
    float* __restrict__ Cf, float* __restrict__ Cf2,
    bf16* __restrict__ Cb, bf16* __restrict__ Cb2,
    const float* __restrict__ bias, int N, int K) {
  __shared__ __align__(16) bf16 As[128 * 32];
  __shared__ __align__(16) bf16 Bs[128 * 32];
  const int tid = threadIdx.x;
  const int lane = tid & 63;
  const int wave = tid >> 6;
  const long row0 = (long)blockIdx.y * 128;
  const long col0 = (long)blockIdx.x * 128;
  const int wr = (wave >> 1) * 64;  // wave row quadrant
  const int wc = (wave & 1) * 64;   // wave col quadrant

  f32x4 acc[4][4];
#pragma unroll
  for (int i = 0; i < 4; i++)
#pragma unroll
    for (int j = 0; j < 4; j++) acc[i][j] = (f32x4){0.f, 0.f, 0.f, 0.f};

  const int srow = tid >> 2;
  const int scol = (tid & 3) * 8;
  const bf16* gA0 = A + (row0 + srow) * (long)K + scol;
  const bf16* gA1 = A + (row0 + srow + 64) * (long)K + scol;
  const bf16* gB0 = B + (col0 + srow) * (long)K + scol;
  const bf16* gB1 = B + (col0 + srow + 64) * (long)K + scol;
  bf16* lA0 = As + wave * 512 + lane * 8;
  bf16* lA1 = As + 64 * 32 + wave * 512 + lane * 8;
  bf16* lB0 = Bs + wave * 512 + lane * 8;
  bf16* lB1 = Bs + 64 * 32 + wave * 512 + lane * 8;

  const int fm = lane & 15;
  const int fk = (lane >> 4) * 8;

  for (int k0 = 0; k0 < K; k0 += 32) {
    GLOAD_LDS16(gA0 + k0, lA0);
    GLOAD_LDS16(gA1 + k0, lA1);
    GLOAD_LDS16(gB0 + k0, lB0);
    GLOAD_LDS16(gB1 + k0, lB1);
    __syncthreads();
    bf16x8 af[4], bfv[4];
#pragma unroll
    for (int i = 0; i < 4; i++)
      af[i] = *(const bf16x8*)(As + (wr + i * 16 + fm) * 32 + fk);
#pragma unroll
    for (int j = 0; j < 4; j++)
      bfv[j] = *(const bf16x8*)(Bs + (wc + j * 16 + fm) * 32 + fk);
#pragma unroll
    for (int i = 0; i < 4; i++)
#pragma unroll
      for (int j = 0; j < 4; j++)
        acc[i][j] = __builtin_amdgcn_mfma_f32_16x16x32_bf16(
            af[i], bfv[j], acc[i][j], 0, 0, 0);
    __syncthreads();
  }

  const int er = (lane >> 4) * 4;
  const int ec = lane & 15;
#pragma unroll
  for (int i = 0; i < 4; i++) {
#pragma unroll
    for (int j = 0; j < 4; j++) {
      const long col = col0 + wc + j * 16 + ec;
      const long rw = row0 + wr + i * 16 + er;
#pragma unroll
      for (int r = 0; r < 4; r++) {
        const float v = acc[i][j][r];
        const long row = rw + r;
        if (EPI == 0) {
          Cf[row * (long)N + col] = v;
        } else if (EPI == 1) {
          if (col < 2048) {
            float z = v + bias[col];
            z = (z > 20.0f) ? z : log1pf(__expf(z));
            Cf[row * 2048 + col] = z;
          } else if (col < 2080) {
            Cf2[row * 32 + (col - 2048)] = v;
          }
        } else {  // EPI == 2
          if (col < 2048) {
            Cb[row * 2048 + col] = (bf16)v;
          } else {
            const float s = v / (1.0f + __expf(-v));
            Cb2[row * 2048 + (col - 2048)] = (bf16)s;
          }
        }
      }
    }
  }
}

// ---------------------------------------------------------------------------
// 4. depthwise causal conv (K=4) + silu.  xin: ROWS x 2048 bf16
// ---------------------------------------------------------------------------
__global__ __launch_bounds__(256) void conv_silu_kernel(
    const bf16* __restrict__ xin, const float* __restrict__ conv_w,
    const float* __restrict__ conv_b, bf16* __restrict__ xc16) {
  const int c = blockIdx.x * 256 + threadIdx.x;  // channel 0..2047
  const int r = blockIdx.y;                      // global row 0..8191
  const int l = r & (SEQ - 1);                   // position within sequence
  const float4 w = *(const float4*)(conv_w + c * 4);
  float acc = conv_b[c];
#pragma unroll
  for (int j = 0; j < 4; j++) {
    const int lp = l - 3 + j;
    const float xv = (lp >= 0) ? (float)xin[(long)(r - 3 + j) * INNER + c] : 0.0f;
    acc += xv * ((const float*)&w)[j];
  }
  const float s = acc / (1.0f + __expf(-acc));  // silu
  xc16[(long)r * INNER + c] = (bf16)s;
}

// ---------------------------------------------------------------------------
// 6a. scan pass 1: per-chunk zero-init scan -> h_end0[16] + dt-sum.
// Channel-per-lane: block=256 ch, grid (INNER/256, NC, BATCH).
// hend layout: [((b*NC+c)*16+s)*INNER + ch]; dtsum: [(b*NC+c)*INNER + ch].
// ---------------------------------------------------------------------------
__global__ __launch_bounds__(256) void scan_pass1_kernel(
    const float* __restrict__ dtm, const float* __restrict__ bc,
    const bf16* __restrict__ xc, const float* __restrict__ A2,
    float* __restrict__ hend, float* __restrict__ dtsum) {
  const int ch = blockIdx.x * 256 + threadIdx.x;
  const int c = blockIdx.y;
  const int b = blockIdx.z;
  const long row0 = (long)b * SEQ + (long)c * CHUNK;

  float a2[16];
#pragma unroll
  for (int q = 0; q < 4; q++) {
    const float4 t = ((const float4*)(A2 + (long)ch * 16))[q];
    a2[q * 4 + 0] = t.x; a2[q * 4 + 1] = t.y;
    a2[q * 4 + 2] = t.z; a2[q * 4 + 3] = t.w;
  }
  float h[16];
#pragma unroll
  for (int s = 0; s < 16; s++) h[s] = 0.0f;
  float dts = 0.0f;

  float dtq[PF2], xcq[PF2];
#pragma unroll
  for (int p = 0; p < PF2; p++) {
    const long r2 = row0 + p;
    dtq[p] = dtm[r2 * INNER + ch];
    xcq[p] = (float)xc[r2 * INNER + ch];
  }
  for (int l0 = 0; l0 <= CHUNK - 2 * PF2; l0 += PF2) {
#pragma unroll
    for (int p = 0; p < PF2; p++) {
      const float dt = dtq[p], xcv = xcq[p];
      const long rp = row0 + l0 + p + PF2;
      dtq[p] = dtm[rp * INNER + ch];
      xcq[p] = (float)xc[rp * INNER + ch];
      const long r = row0 + l0 + p;
      float Bv[16];  // wave-uniform -> scalar loads
#pragma unroll
      for (int k = 0; k < 16; k++) Bv[k] = bc[r * 32 + k];
      dts += dt;
      const float u = dt * xcv;
#pragma unroll
      for (int s = 0; s < 16; s++)
        h[s] = exp2f(a2[s] * dt) * h[s] + Bv[s] * u;
    }
  }
#pragma unroll
  for (int p = 0; p < PF2; p++) {
    const float dt = dtq[p], xcv = xcq[p];
    const long r = row0 + CHUNK - PF2 + p;
    float Bv[16];
#pragma unroll
    for (int k = 0; k < 16; k++) Bv[k] = bc[r * 32 + k];
    dts += dt;
    const float u = dt * xcv;
#pragma unroll
    for (int s = 0; s < 16; s++)
      h[s] = exp2f(a2[s] * dt) * h[s] + Bv[s] * u;
  }

  const long cb = (long)(b * NC + c);
#pragma unroll
  for (int s = 0; s < 16; s++) hend[(cb * 16 + s) * INNER + ch] = h[s];
  dtsum[cb * INNER + ch] = dts;
}

// ---------------------------------------------------------------------------
// 6b. combine: sequential over NC chunks; rewrites hend -> h_start in place.
// One thread per (b, s, ch).
// ---------------------------------------------------------------------------
__global__ __launch_bounds__(256) void scan_combine_kernel(
    float* __restrict__ hio, const float* __restrict__ dtsum,
    const float* __restrict__ A2) {
  const int idx = blockIdx.x * 256 + threadIdx.x;  // < BATCH*16*INNER
  const int ch = idx & (INNER - 1);
  const int s = (idx >> 11) & 15;
  const int b = idx >> 15;
  const float a2 = A2[(long)ch * 16 + s];
  float H = 0.0f;
  for (int c = 0; c < NC; c++) {
    const long cb = (long)(b * NC + c);
    const long o = (cb * 16 + s) * INNER + ch;
    const float he = hio[o];
    const float ds = dtsum[cb * INNER + ch];
    hio[o] = H;  // h_start for chunk c
    H = exp2f(a2 * ds) * H + he;
  }
}

// ---------------------------------------------------------------------------
// 6c. scan pass 3: re-scan chunk from true h_start; y = (C.h + D*xc)*silu(res)
// ---------------------------------------------------------------------------
__global__ __launch_bounds__(256) void scan_pass3_kernel(
    const float* __restrict__ dtm, const float* __restrict__ bc,
    const bf16* __restrict__ xc, const bf16* __restrict__ rs,
    const float* __restrict__ A2, const float* __restrict__ Dv,
    const float* __restrict__ hstart, bf16* __restrict__ y) {
  const int ch = blockIdx.x * 256 + threadIdx.x;
  const int c = blockIdx.y;
  const int b = blockIdx.z;
  const long row0 = (long)b * SEQ + (long)c * CHUNK;

  float a2[16];
#pragma unroll
  for (int q = 0; q < 4; q++) {
    const float4 t = ((const float4*)(A2 + (long)ch * 16))[q];
    a2[q * 4 + 0] = t.x; a2[q * 4 + 1] = t.y;
    a2[q * 4 + 2] = t.z; a2[q * 4 + 3] = t.w;
  }
  const float d = Dv[ch];
  const long cb = (long)(b * NC + c);
  float h[16];
#pragma unroll
  for (int s = 0; s < 16; s++) h[s] = hstart[(cb * 16 + s) * INNER + ch];

  float dtq[PF2], xcq[PF2], rsq[PF2];
#pragma unroll
  for (int p = 0; p < PF2; p++) {
    const long r2 = row0 + p;
    dtq[p] = dtm[r2 * INNER + ch];
    xcq[p] = (float)xc[r2 * INNER + ch];
    rsq[p] = (float)rs[r2 * INNER + ch];
  }
  for (int l0 = 0; l0 <= CHUNK - 2 * PF2; l0 += PF2) {
#pragma unroll
    for (int p = 0; p < PF2; p++) {
      const float dt = dtq[p], xcv = xcq[p], rsv = rsq[p];
      const long rp = row0 + l0 + p + PF2;
      dtq[p] = dtm[rp * INNER + ch];
      xcq[p] = (float)xc[rp * INNER + ch];
      rsq[p] = (float)rs[rp * INNER + ch];
      const long r = row0 + l0 + p;
      float Bv[16], Cv[16];  // wave-uniform -> scalar loads
#pragma unroll
      for (int k = 0; k < 16; k++) Bv[k] = bc[r * 32 + k];
#pragma unroll
      for (int k = 0; k < 16; k++) Cv[k] = bc[r * 32 + 16 + k];
      const float u = dt * xcv;
      float yv = d * xcv;
#pragma unroll
      for (int s = 0; s < 16; s++) {
        h[s] = exp2f(a2[s] * dt) * h[s] + Bv[s] * u;
        yv += h[s] * Cv[s];
      }
      y[r * INNER + ch] = (bf16)(yv * rsv);
    }
  }
#pragma unroll
  for (int p = 0; p < PF2; p++) {
    const float dt = dtq[p], xcv = xcq[p], rsv = rsq[p];
    const long r = row0 + CHUNK - PF2 + p;
    float Bv[16], Cv[16];
#pragma unroll
    for (int k = 0; k < 16; k++) Bv[k] = bc[r * 32 + k];
#pragma unroll
    for (int k = 0; k < 16; k++) Cv[k] = bc[r * 32 + 16 + k];
    const float u = dt * xcv;
    float yv = d * xcv;
#pragma unroll
    for (int s = 0; s < 16; s++) {
      h[s] = exp2f(a2[s] * dt) * h[s] + Bv[s] * u;
      yv += h[s] * Cv[s];
    }
    y[r * INNER + ch] = (bf16)(yv * rsv);
  }
}

// ---------------------------------------------------------------------------
// launch
// ---------------------------------------------------------------------------
extern "C" void kernel_launch(void* const* d_in, const int* in_sizes, int n_in,
                              void* d_out, int out_size, void* d_ws,
                              size_t ws_size, hipStream_t stream) {
  (void)in_sizes; (void)n_in; (void)out_size;
  const float* x      = (const float*)d_in[0];
  const float* w_norm = (const float*)d_in[1];
  const float* W_in   = (const float*)d_in[2];
  const float* conv_w = (const float*)d_in[3];
  const float* conv_b = (const float*)d_in[4];
  const float* W_dt   = (const float*)d_in[5];
  const float* b_dt   = (const float*)d_in[6];
  const float* W_B    = (const float*)d_in[7];
  const float* W_C    = (const float*)d_in[8];
  const float* A_log  = (const float*)d_in[9];
  const float* Dv     = (const float*)d_in[10];
  const float* W_out  = (const float*)d_in[11];
  float* out = (float*)d_out;

  // ---- workspace layout (lifetime-aliased, 173.625 MiB total) -------------
  const size_t MB = 1024ull * 1024ull;
  char* base = (char*)d_ws;
  bf16*  xnorm  = (bf16*)(base + 0);          // 16 MiB [rmsnorm -> gemm1]
  bf16*  win_b  = (bf16*)(base + 16 * MB);    //  8 MiB [pack -> gemm1]
  bf16*  xin_b  = (bf16*)(base + 24 * MB);    // 32 MiB [gemm1 -> conv]
  float* dtm    = (float*)(base + 0);         // 64 MiB [gemm2 -> scan] ALIAS
  float* bcm    = (float*)(base + 64 * MB);   //  1 MiB [gemm2 -> scan]
  bf16*  res_b  = (bf16*)(base + 65 * MB);    // 32 MiB [gemm1 -> scan]
  bf16*  xc_b   = (bf16*)(base + 97 * MB);    // 32 MiB [conv -> gemm2, scan]
  bf16*  wdtbcb = (bf16*)(base + 129 * MB);   // 8.5 MiB [pack -> gemm2]
  // chunk state aliases wdtbcb (dead after gemm2): 8 MiB hend + 0.5 MiB dtsum
  float* hend   = (float*)(base + 129 * MB);                 // 8 MiB
  float* dtsum  = (float*)(base + 137 * MB);                 // 0.5 MiB
  char*  p2     = base + 129 * MB + (size_t)NBC * INNER * 2;
  bf16*  wout_b = (bf16*)p2;                  //  4 MiB [pack -> gemm3]
  float* A2     = (float*)(p2 + (size_t)DIM * INNER * 2);  // 128 KiB
  bf16*  yb     = (bf16*)(p2 + (size_t)DIM * INNER * 2 +
                          (size_t)INNER * STATE * 4);      // 32 MiB [scan->g3]
  const size_t NEEDED = (size_t)((char*)yb - base) + (size_t)ROWS * INNER * 2;

  if (ws_size < NEEDED) {  // diagnostic: fail with absmax == ws_size
    ws_report_kernel<<<1, 64, 0, stream>>>(out, (float)ws_size, (float)NEEDED);
    return;
  }

  // 1. rmsnorm -> xnorm bf16
  rmsnorm_kernel<<<ROWS, 256, 0, stream>>>(x, w_norm, xnorm);

  // 2. weight packs
  cvt_bf16_kernel<<<(N1 * DIM) / 256, 256, 0, stream>>>(W_in, win_b, N1 * DIM);
  build_wdtbc_kernel<<<(NBC * INNER) / 256, 256, 0, stream>>>(W_dt, W_B, W_C,
                                                              wdtbcb);
  cvt_bf16_kernel<<<(DIM * INNER) / 256, 256, 0, stream>>>(W_out, wout_b,
                                                           DIM * INNER);
  build_a2_kernel<<<(INNER * STATE) / 256, 256, 0, stream>>>(A_log, A2);

  // 3. GEMM1: xnorm(8192x1024) @ W_in^T(4096x1024) -> xin_b | silu->res_b
  gemm_bf16_kernel<2><<<dim3(N1 / 128, ROWS / 128), 256, 0, stream>>>(
      xnorm, win_b, nullptr, nullptr, xin_b, res_b, nullptr, N1, DIM);

  // 4. conv + silu -> xc_b
  conv_silu_kernel<<<dim3(INNER / 256, ROWS), 256, 0, stream>>>(
      xin_b, conv_w, conv_b, xc_b);

  // 5. GEMM2: xc_b(8192x2048) @ [Wdt;WB;WC]^T(2176x2048) -> dtm | bcm
  gemm_bf16_kernel<1><<<dim3(NBC / 128, ROWS / 128), 256, 0, stream>>>(
      xc_b, wdtbcb, dtm, bcm, nullptr, nullptr, b_dt, NBC, INNER);

  // 6. chunked scan: pass1 -> combine -> pass3
  scan_pass1_kernel<<<dim3(INNER / 256, NC, BATCH), 256, 0, stream>>>(
      dtm, bcm, xc_b, A2, hend, dtsum);
  scan_combine_kernel<<<(BATCH * 16 * INNER) / 256, 256, 0, stream>>>(
      hend, dtsum, A2);
  scan_pass3_kernel<<<dim3(INNER / 256, NC, BATCH), 256, 0, stream>>>(
      dtm, bcm, xc_b, res_b, A2, Dv, hend, yb);

  // 7. GEMM3: yb(8192x2048) @ W_out^T(1024x2048) -> out f32
  gemm_bf16_kernel<0><<<dim3(DIM / 128, ROWS / 128), 256, 0, stream>>>(
      yb, wout_b, out, nullptr, nullptr, nullptr, nullptr, DIM, INNER);
}

// Round 5
// 699.458 us; speedup vs baseline: 1.8507x; 1.0095x over previous
//
#include <hip/hip_runtime.h>

// ---------------------------------------------------------------------------
// MambaBlock on MI355X (gfx950).  Pipeline:
//   1. rmsnorm         : x f32 (8192x1024) -> xnorm bf16
//   2. weight packs    : W_in, [W_dt;W_B;W_C;pad] (2176x2048), W_out -> bf16;
//                        A2 = -exp(A_log)*log2(e)
//   3. gemm<SPLIT_IN>  : xnorm @ W_in^T -> x_inner bf16 | silu(res) bf16
//   4. conv_silu       : depthwise causal K=4 + silu -> xconv bf16
//   5. gemm<SPLIT_DT>  : xconv @ [Wdt;WB;WC]^T -> dt f32 (softplus) | bc f32
//   6. scan            : chunked two-pass associative scan, channel-per-lane
//   7. gemm<PLAIN>     : y @ W_out^T -> d_out f32
// GEMM: m97 structure - 128x128 tile, BK=32, 4 waves, mfma_f32_16x16x32_bf16.
// R5: XCD-band swizzle (bid&7 -> contiguous row-tile band per XCD).  R4 PMC:
// FETCH 229 MB vs 42 ideal (5.4x over-fetch, cross-XCD A-stripe duplication)
// -> HBM-latency barrier drains -> MfmaUtil 15%.  Bands make A disjoint per
// XCD (fetched once chip-wide); B shared via L3.  EPI branches block-uniform.
// Workspace: 173.625 MiB; chunk state (8.5 MB) aliases dead wdtbcb region.
// ---------------------------------------------------------------------------

typedef __bf16 bf16;
typedef __attribute__((ext_vector_type(8))) __bf16 bf16x8;
typedef __attribute__((ext_vector_type(4))) float f32x4;

#define DIM   1024
#define STATE 16
#define INNER 2048
#define BATCH 4
#define SEQ   2048
#define ROWS  (BATCH * SEQ)      // 8192
#define N1    (2 * INNER)        // 4096 (GEMM1 N)
#define NBC   2176               // 2048 dt + 16 B + 16 C + 96 pad
#define CHUNK 128                // scan chunk length
#define NC    (SEQ / CHUNK)      // 16 chunks per sequence
#define PF2   4                  // scan prefetch depth (rows)

// async global->LDS, 16 bytes per lane (lane-contiguous LDS dest)
#define GLOAD_LDS16(g, l)                                                  \
  __builtin_amdgcn_global_load_lds(                                        \
      (const __attribute__((address_space(1))) unsigned int*)(g),          \
      (__attribute__((address_space(3))) unsigned int*)(l), 16, 0, 0)

// ---------------------------------------------------------------------------
// 0. workspace-too-small diagnostic
// ---------------------------------------------------------------------------
__global__ void ws_report_kernel(float* out, float wssz, float need) {
  if (threadIdx.x == 0) { out[0] = wssz; out[1] = need; }
}

// ---------------------------------------------------------------------------
// 1. RMSNorm: one block per row (1024 floats), 256 threads x float4
// ---------------------------------------------------------------------------
__global__ __launch_bounds__(256) void rmsnorm_kernel(
    const float* __restrict__ x, const float* __restrict__ w,
    bf16* __restrict__ out) {
  const int row = blockIdx.x;
  const int t = threadIdx.x;
  const float4 v = ((const float4*)(x + (long)row * DIM))[t];
  float ss = v.x * v.x + v.y * v.y + v.z * v.z + v.w * v.w;
#pragma unroll
  for (int off = 32; off > 0; off >>= 1) ss += __shfl_xor(ss, off, 64);
  __shared__ float red[4];
  if ((t & 63) == 0) red[t >> 6] = ss;
  __syncthreads();
  const float tot = red[0] + red[1] + red[2] + red[3];
  const float scale = rsqrtf(tot * (1.0f / DIM) + 1e-6f);
  const float4 wv = ((const float4*)w)[t];
  bf16* o = out + (long)row * DIM + t * 4;
  o[0] = (bf16)(v.x * scale * wv.x);
  o[1] = (bf16)(v.y * scale * wv.y);
  o[2] = (bf16)(v.z * scale * wv.z);
  o[3] = (bf16)(v.w * scale * wv.w);
}

// ---------------------------------------------------------------------------
// 2. weight packs
// ---------------------------------------------------------------------------
__global__ __launch_bounds__(256) void cvt_bf16_kernel(
    const float* __restrict__ src, bf16* __restrict__ dst, int n) {
  const int i = blockIdx.x * 256 + threadIdx.x;
  if (i < n) dst[i] = (bf16)src[i];
}

__global__ __launch_bounds__(256) void build_wdtbc_kernel(
    const float* __restrict__ Wdt, const float* __restrict__ WB,
    const float* __restrict__ WC, bf16* __restrict__ dst) {
  const long i = (long)blockIdx.x * 256 + threadIdx.x;  // < NBC*INNER
  const long r = i >> 11;  // / INNER
  const long k = i & (INNER - 1);
  float v = 0.0f;
  if (r < 2048) v = Wdt[r * INNER + k];
  else if (r < 2064) v = WB[(r - 2048) * INNER + k];
  else if (r < 2080) v = WC[(r - 2064) * INNER + k];
  dst[i] = (bf16)v;
}

__global__ __launch_bounds__(256) void build_a2_kernel(
    const float* __restrict__ A_log, float* __restrict__ A2) {
  const int i = blockIdx.x * 256 + threadIdx.x;  // < INNER*STATE
  A2[i] = -__expf(A_log[i]) * 1.4426950408889634f;  // A * log2(e)
}

// ---------------------------------------------------------------------------
// 3/5/7. GEMM: C[M,N] = A[M,K] @ B[N,K]^T  (A,B bf16 row-major, f32 acc)
// 1D grid (nb = nx*ny blocks, nb % 8 == 0), XCD-band swizzled.
// EPI 0: plain f32 -> Cf (stride N)
// EPI 1: tile col0<2048 -> softplus(acc+bias) -> Cf; col0==2048 tile ->
//        cols 2048..2079 -> Cf2 (stride 32)
// EPI 2: tile col0<2048 -> bf16 -> Cb; else silu -> Cb2 (both stride 2048)
// ---------------------------------------------------------------------------
template <int EPI>
__global__ __launch_bounds__(256) void gemm_bf16_kernel(
    const bf16* __restrict__ A, const bf16* __restrict__ B,
    float* __restrict__ Cf, float* __restrict__ Cf2,
    bf16* __restrict__ Cb, bf16* __restrict__ Cb2,
    const float* __restrict__ bias, int nx, int N, int K) {
  __shared__ __align__(16) bf16 As[128 * 32];
  __shared__ __align__(16) bf16 Bs[128 * 32];
  const int tid = threadIdx.x;
  const int lane = tid & 63;
  const int wave = tid >> 6;

  // XCD-band swizzle: blocks with bid%8==x land on XCD x (round-robin
  // dispatch assumption); give each XCD a contiguous band of row-tiles so
  // A-stripes are disjoint per XCD (each fetched once chip-wide), B shared
  // across XCDs via L3.
  const int per = gridDim.x >> 3;
  const int lin = (blockIdx.x & 7) * per + (blockIdx.x >> 3);
  const int row_t = lin / nx;
  const int col_t = lin - row_t * nx;
  const long row0 = (long)row_t * 128;
  const long col0 = (long)col_t * 128;

  const int wr = (wave >> 1) * 64;  // wave row quadrant
  const int wc = (wave & 1) * 64;   // wave col quadrant

  f32x4 acc[4][4];
#pragma unroll
  for (int i = 0; i < 4; i++)
#pragma unroll
    for (int j = 0; j < 4; j++) acc[i][j] = (f32x4){0.f, 0.f, 0.f, 0.f};

  const int srow = tid >> 2;
  const int scol = (tid & 3) * 8;
  const bf16* gA0 = A + (row0 + srow) * (long)K + scol;
  const bf16* gA1 = A + (row0 + srow + 64) * (long)K + scol;
  const bf16* gB0 = B + (col0 + srow) * (long)K + scol;
  const bf16* gB1 = B + (col0 + srow + 64) * (long)K + scol;
  bf16* lA0 = As + wave * 512 + lane * 8;
  bf16* lA1 = As + 64 * 32 + wave * 512 + lane * 8;
  bf16* lB0 = Bs + wave * 512 + lane * 8;
  bf16* lB1 = Bs + 64 * 32 + wave * 512 + lane * 8;

  const int fm = lane & 15;
  const int fk = (lane >> 4) * 8;

  for (int k0 = 0; k0 < K; k0 += 32) {
    GLOAD_LDS16(gA0 + k0, lA0);
    GLOAD_LDS16(gA1 + k0, lA1);
    GLOAD_LDS16(gB0 + k0, lB0);
    GLOAD_LDS16(gB1 + k0, lB1);
    __syncthreads();
    bf16x8 af[4], bfv[4];
#pragma unroll
    for (int i = 0; i < 4; i++)
      af[i] = *(const bf16x8*)(As + (wr + i * 16 + fm) * 32 + fk);
#pragma unroll
    for (int j = 0; j < 4; j++)
      bfv[j] = *(const bf16x8*)(Bs + (wc + j * 16 + fm) * 32 + fk);
#pragma unroll
    for (int i = 0; i < 4; i++)
#pragma unroll
      for (int j = 0; j < 4; j++)
        acc[i][j] = __builtin_amdgcn_mfma_f32_16x16x32_bf16(
            af[i], bfv[j], acc[i][j], 0, 0, 0);
    __syncthreads();
  }

  // epilogue: C/D layout col=lane&15, row=(lane>>4)*4+reg  [m89/m91 verified]
  // 2048-boundary is tile-aligned -> branch on col0 is block-uniform.
  const int er = (lane >> 4) * 4;
  const int ec = lane & 15;
#pragma unroll
  for (int i = 0; i < 4; i++) {
#pragma unroll
    for (int j = 0; j < 4; j++) {
      const long col = col0 + wc + j * 16 + ec;
      const long rw = row0 + wr + i * 16 + er;
#pragma unroll
      for (int r = 0; r < 4; r++) {
        const float v = acc[i][j][r];
        const long row = rw + r;
        if (EPI == 0) {
          Cf[row * (long)N + col] = v;
        } else if (EPI == 1) {
          if (col0 < 2048) {
            float z = v + bias[col];
            z = (z > 20.0f) ? z : log1pf(__expf(z));
            Cf[row * 2048 + col] = z;
          } else if (col < 2080) {  // uniform per (wc,j): wc==0 && j<2
            Cf2[row * 32 + (col - 2048)] = v;
          }
        } else {  // EPI == 2
          if (col0 < 2048) {
            Cb[row * 2048 + col] = (bf16)v;
          } else {
            const float s = v / (1.0f + __expf(-v));
            Cb2[row * 2048 + (col - 2048)] = (bf16)s;
          }
        }
      }
    }
  }
}

// ---------------------------------------------------------------------------
// 4. depthwise causal conv (K=4) + silu.  xin: ROWS x 2048 bf16
// ---------------------------------------------------------------------------
__global__ __launch_bounds__(256) void conv_silu_kernel(
    const bf16* __restrict__ xin, const float* __restrict__ conv_w,
    const float* __restrict__ conv_b, bf16* __restrict__ xc16) {
  const int c = blockIdx.x * 256 + threadIdx.x;  // channel 0..2047
  const int r = blockIdx.y;                      // global row 0..8191
  const int l = r & (SEQ - 1);                   // position within sequence
  const float4 w = *(const float4*)(conv_w + c * 4);
  float acc = conv_b[c];
#pragma unroll
  for (int j = 0; j < 4; j++) {
    const int lp = l - 3 + j;
    const float xv = (lp >= 0) ? (float)xin[(long)(r - 3 + j) * INNER + c] : 0.0f;
    acc += xv * ((const float*)&w)[j];
  }
  const float s = acc / (1.0f + __expf(-acc));  // silu
  xc16[(long)r * INNER + c] = (bf16)s;
}

// ---------------------------------------------------------------------------
// 6a. scan pass 1: per-chunk zero-init scan -> h_end0[16] + dt-sum.
// Channel-per-lane: block=256 ch, grid (INNER/256, NC, BATCH).
// hend layout: [((b*NC+c)*16+s)*INNER + ch]; dtsum: [(b*NC+c)*INNER + ch].
// ---------------------------------------------------------------------------
__global__ __launch_bounds__(256) void scan_pass1_kernel(
    const float* __restrict__ dtm, const float* __restrict__ bc,
    const bf16* __restrict__ xc, const float* __restrict__ A2,
    float* __restrict__ hend, float* __restrict__ dtsum) {
  const int ch = blockIdx.x * 256 + threadIdx.x;
  const int c = blockIdx.y;
  const int b = blockIdx.z;
  const long row0 = (long)b * SEQ + (long)c * CHUNK;

  float a2[16];
#pragma unroll
  for (int q = 0; q < 4; q++) {
    const float4 t = ((const float4*)(A2 + (long)ch * 16))[q];
    a2[q * 4 + 0] = t.x; a2[q * 4 + 1] = t.y;
    a2[q * 4 + 2] = t.z; a2[q * 4 + 3] = t.w;
  }
  float h[16];
#pragma unroll
  for (int s = 0; s < 16; s++) h[s] = 0.0f;
  float dts = 0.0f;

  float dtq[PF2], xcq[PF2];
#pragma unroll
  for (int p = 0; p < PF2; p++) {
    const long r2 = row0 + p;
    dtq[p] = dtm[r2 * INNER + ch];
    xcq[p] = (float)xc[r2 * INNER + ch];
  }
  for (int l0 = 0; l0 <= CHUNK - 2 * PF2; l0 += PF2) {
#pragma unroll
    for (int p = 0; p < PF2; p++) {
      const float dt = dtq[p], xcv = xcq[p];
      const long rp = row0 + l0 + p + PF2;
      dtq[p] = dtm[rp * INNER + ch];
      xcq[p] = (float)xc[rp * INNER + ch];
      const long r = row0 + l0 + p;
      float Bv[16];  // wave-uniform -> scalar loads
#pragma unroll
      for (int k = 0; k < 16; k++) Bv[k] = bc[r * 32 + k];
      dts += dt;
      const float u = dt * xcv;
#pragma unroll
      for (int s = 0; s < 16; s++)
        h[s] = exp2f(a2[s] * dt) * h[s] + Bv[s] * u;
    }
  }
#pragma unroll
  for (int p = 0; p < PF2; p++) {
    const float dt = dtq[p], xcv = xcq[p];
    const long r = row0 + CHUNK - PF2 + p;
    float Bv[16];
#pragma unroll
    for (int k = 0; k < 16; k++) Bv[k] = bc[r * 32 + k];
    dts += dt;
    const float u = dt * xcv;
#pragma unroll
    for (int s = 0; s < 16; s++)
      h[s] = exp2f(a2[s] * dt) * h[s] + Bv[s] * u;
  }

  const long cb = (long)(b * NC + c);
#pragma unroll
  for (int s = 0; s < 16; s++) hend[(cb * 16 + s) * INNER + ch] = h[s];
  dtsum[cb * INNER + ch] = dts;
}

// ---------------------------------------------------------------------------
// 6b. combine: sequential over NC chunks; rewrites hend -> h_start in place.
// One thread per (b, s, ch).
// ---------------------------------------------------------------------------
__global__ __launch_bounds__(256) void scan_combine_kernel(
    float* __restrict__ hio, const float* __restrict__ dtsum,
    const float* __restrict__ A2) {
  const int idx = blockIdx.x * 256 + threadIdx.x;  // < BATCH*16*INNER
  const int ch = idx & (INNER - 1);
  const int s = (idx >> 11) & 15;
  const int b = idx >> 15;
  const float a2 = A2[(long)ch * 16 + s];
  float H = 0.0f;
  for (int c = 0; c < NC; c++) {
    const long cb = (long)(b * NC + c);
    const long o = (cb * 16 + s) * INNER + ch;
    const float he = hio[o];
    const float ds = dtsum[cb * INNER + ch];
    hio[o] = H;  // h_start for chunk c
    H = exp2f(a2 * ds) * H + he;
  }
}

// ---------------------------------------------------------------------------
// 6c. scan pass 3: re-scan chunk from true h_start; y = (C.h + D*xc)*silu(res)
// ---------------------------------------------------------------------------
__global__ __launch_bounds__(256) void scan_pass3_kernel(
    const float* __restrict__ dtm, const float* __restrict__ bc,
    const bf16* __restrict__ xc, const bf16* __restrict__ rs,
    const float* __restrict__ A2, const float* __restrict__ Dv,
    const float* __restrict__ hstart, bf16* __restrict__ y) {
  const int ch = blockIdx.x * 256 + threadIdx.x;
  const int c = blockIdx.y;
  const int b = blockIdx.z;
  const long row0 = (long)b * SEQ + (long)c * CHUNK;

  float a2[16];
#pragma unroll
  for (int q = 0; q < 4; q++) {
    const float4 t = ((const float4*)(A2 + (long)ch * 16))[q];
    a2[q * 4 + 0] = t.x; a2[q * 4 + 1] = t.y;
    a2[q * 4 + 2] = t.z; a2[q * 4 + 3] = t.w;
  }
  const float d = Dv[ch];
  const long cb = (long)(b * NC + c);
  float h[16];
#pragma unroll
  for (int s = 0; s < 16; s++) h[s] = hstart[(cb * 16 + s) * INNER + ch];

  float dtq[PF2], xcq[PF2], rsq[PF2];
#pragma unroll
  for (int p = 0; p < PF2; p++) {
    const long r2 = row0 + p;
    dtq[p] = dtm[r2 * INNER + ch];
    xcq[p] = (float)xc[r2 * INNER + ch];
    rsq[p] = (float)rs[r2 * INNER + ch];
  }
  for (int l0 = 0; l0 <= CHUNK - 2 * PF2; l0 += PF2) {
#pragma unroll
    for (int p = 0; p < PF2; p++) {
      const float dt = dtq[p], xcv = xcq[p], rsv = rsq[p];
      const long rp = row0 + l0 + p + PF2;
      dtq[p] = dtm[rp * INNER + ch];
      xcq[p] = (float)xc[rp * INNER + ch];
      rsq[p] = (float)rs[rp * INNER + ch];
      const long r = row0 + l0 + p;
      float Bv[16], Cv[16];  // wave-uniform -> scalar loads
#pragma unroll
      for (int k = 0; k < 16; k++) Bv[k] = bc[r * 32 + k];
#pragma unroll
      for (int k = 0; k < 16; k++) Cv[k] = bc[r * 32 + 16 + k];
      const float u = dt * xcv;
      float yv = d * xcv;
#pragma unroll
      for (int s = 0; s < 16; s++) {
        h[s] = exp2f(a2[s] * dt) * h[s] + Bv[s] * u;
        yv += h[s] * Cv[s];
      }
      y[r * INNER + ch] = (bf16)(yv * rsv);
    }
  }
#pragma unroll
  for (int p = 0; p < PF2; p++) {
    const float dt = dtq[p], xcv = xcq[p], rsv = rsq[p];
    const long r = row0 + CHUNK - PF2 + p;
    float Bv[16], Cv[16];
#pragma unroll
    for (int k = 0; k < 16; k++) Bv[k] = bc[r * 32 + k];
#pragma unroll
    for (int k = 0; k < 16; k++) Cv[k] = bc[r * 32 + 16 + k];
    const float u = dt * xcv;
    float yv = d * xcv;
#pragma unroll
    for (int s = 0; s < 16; s++) {
      h[s] = exp2f(a2[s] * dt) * h[s] + Bv[s] * u;
      yv += h[s] * Cv[s];
    }
    y[r * INNER + ch] = (bf16)(yv * rsv);
  }
}

// ---------------------------------------------------------------------------
// launch
// ---------------------------------------------------------------------------
extern "C" void kernel_launch(void* const* d_in, const int* in_sizes, int n_in,
                              void* d_out, int out_size, void* d_ws,
                              size_t ws_size, hipStream_t stream) {
  (void)in_sizes; (void)n_in; (void)out_size;
  const float* x      = (const float*)d_in[0];
  const float* w_norm = (const float*)d_in[1];
  const float* W_in   = (const float*)d_in[2];
  const float* conv_w = (const float*)d_in[3];
  const float* conv_b = (const float*)d_in[4];
  const float* W_dt   = (const float*)d_in[5];
  const float* b_dt   = (const float*)d_in[6];
  const float* W_B    = (const float*)d_in[7];
  const float* W_C    = (const float*)d_in[8];
  const float* A_log  = (const float*)d_in[9];
  const float* Dv     = (const float*)d_in[10];
  const float* W_out  = (const float*)d_in[11];
  float* out = (float*)d_out;

  // ---- workspace layout (lifetime-aliased, 173.625 MiB total) -------------
  const size_t MB = 1024ull * 1024ull;
  char* base = (char*)d_ws;
  bf16*  xnorm  = (bf16*)(base + 0);          // 16 MiB [rmsnorm -> gemm1]
  bf16*  win_b  = (bf16*)(base + 16 * MB);    //  8 MiB [pack -> gemm1]
  bf16*  xin_b  = (bf16*)(base + 24 * MB);    // 32 MiB [gemm1 -> conv]
  float* dtm    = (float*)(base + 0);         // 64 MiB [gemm2 -> scan] ALIAS
  float* bcm    = (float*)(base + 64 * MB);   //  1 MiB [gemm2 -> scan]
  bf16*  res_b  = (bf16*)(base + 65 * MB);    // 32 MiB [gemm1 -> scan]
  bf16*  xc_b   = (bf16*)(base + 97 * MB);    // 32 MiB [conv -> gemm2, scan]
  bf16*  wdtbcb = (bf16*)(base + 129 * MB);   // 8.5 MiB [pack -> gemm2]
  // chunk state aliases wdtbcb (dead after gemm2): 8 MiB hend + 0.5 MiB dtsum
  float* hend   = (float*)(base + 129 * MB);                 // 8 MiB
  float* dtsum  = (float*)(base + 137 * MB);                 // 0.5 MiB
  char*  p2     = base + 129 * MB + (size_t)NBC * INNER * 2;
  bf16*  wout_b = (bf16*)p2;                  //  4 MiB [pack -> gemm3]
  float* A2     = (float*)(p2 + (size_t)DIM * INNER * 2);  // 128 KiB
  bf16*  yb     = (bf16*)(p2 + (size_t)DIM * INNER * 2 +
                          (size_t)INNER * STATE * 4);      // 32 MiB [scan->g3]
  const size_t NEEDED = (size_t)((char*)yb - base) + (size_t)ROWS * INNER * 2;

  if (ws_size < NEEDED) {  // diagnostic: fail with absmax == ws_size
    ws_report_kernel<<<1, 64, 0, stream>>>(out, (float)ws_size, (float)NEEDED);
    return;
  }

  // 1. rmsnorm -> xnorm bf16
  rmsnorm_kernel<<<ROWS, 256, 0, stream>>>(x, w_norm, xnorm);

  // 2. weight packs
  cvt_bf16_kernel<<<(N1 * DIM) / 256, 256, 0, stream>>>(W_in, win_b, N1 * DIM);
  build_wdtbc_kernel<<<(NBC * INNER) / 256, 256, 0, stream>>>(W_dt, W_B, W_C,
                                                              wdtbcb);
  cvt_bf16_kernel<<<(DIM * INNER) / 256, 256, 0, stream>>>(W_out, wout_b,
                                                           DIM * INNER);
  build_a2_kernel<<<(INNER * STATE) / 256, 256, 0, stream>>>(A_log, A2);

  // 3. GEMM1: xnorm(8192x1024) @ W_in^T(4096x1024) -> xin_b | silu->res_b
  gemm_bf16_kernel<2><<<(N1 / 128) * (ROWS / 128), 256, 0, stream>>>(
      xnorm, win_b, nullptr, nullptr, xin_b, res_b, nullptr, N1 / 128, N1,
      DIM);

  // 4. conv + silu -> xc_b
  conv_silu_kernel<<<dim3(INNER / 256, ROWS), 256, 0, stream>>>(
      xin_b, conv_w, conv_b, xc_b);

  // 5. GEMM2: xc_b(8192x2048) @ [Wdt;WB;WC]^T(2176x2048) -> dtm | bcm
  gemm_bf16_kernel<1><<<(NBC / 128) * (ROWS / 128), 256, 0, stream>>>(
      xc_b, wdtbcb, dtm, bcm, nullptr, nullptr, b_dt, NBC / 128, NBC, INNER);

  // 6. chunked scan: pass1 -> combine -> pass3
  scan_pass1_kernel<<<dim3(INNER / 256, NC, BATCH), 256, 0, stream>>>(
      dtm, bcm, xc_b, A2, hend, dtsum);
  scan_combine_kernel<<<(BATCH * 16 * INNER) / 256, 256, 0, stream>>>(
      hend, dtsum, A2);
  scan_pass3_kernel<<<dim3(INNER / 256, NC, BATCH), 256, 0, stream>>>(
      dtm, bcm, xc_b, res_b, A2, Dv, hend, yb);

  // 7. GEMM3: yb(8192x2048) @ W_out^T(1024x2048) -> out f32
  gemm_bf16_kernel<0><<<(DIM / 128) * (ROWS / 128), 256, 0, stream>>>(
      yb, wout_b, out, nullptr, nullptr, nullptr, nullptr, DIM / 128, DIM,
      INNER);
}